// Round 10
// baseline (712.404 us; speedup 1.0000x reference)
//
#include <hip/hip_runtime.h>
#include <hip/hip_bf16.h>
#include <stdint.h>

#define N_OBS 65536
#define N_DIM 256
#define N_FUN 16
#define N_APP 8
#define MT 64
#define STRIDE 66560          // N_OBS + N_FUN*MT
#define MAXT 1040             // STRIDE/64
#define N_BLK 256

typedef __attribute__((ext_vector_type(8))) short v8s;
typedef __attribute__((ext_vector_type(4))) short v4s;
typedef __attribute__((ext_vector_type(4))) float v4f;

__device__ __forceinline__ unsigned short f2bf(float f) {
  union { float f; uint32_t u; } v;
  v.f = f;
  uint32_t u = v.u;
  return (unsigned short)((u + 0x7FFFu + ((u >> 16) & 1u)) >> 16);
}

// bijective XCD swizzle (grid % 8 == 0): consecutive work -> same XCD L2
__device__ __forceinline__ int xcd_swz(int bid, int n) {
  int q = n >> 3;
  return (bid & 7) * q + (bid >> 3);
}

__global__ void k_init(int* __restrict__ perm, int total) {
  int tid = blockIdx.x * 256 + threadIdx.x;
  if (tid < total) perm[tid] = -1;
}

// W (f,d,e) f32 -> Wt (f,e,d) bf16  (n-major, k contiguous)
__global__ void k_prep_w(const float* __restrict__ W, unsigned short* __restrict__ Wt) {
  int tid = blockIdx.x * 256 + threadIdx.x;
  int f = tid >> 16, n = (tid >> 8) & 255, k = tid & 255;
  Wt[tid] = f2bf(W[(f << 16) | (k << 8) | n]);
}

// per-block histogram: blockCnt[bin*N_BLK + block], bin = t*16+f (128 bins)
__global__ void k_hist(const int* __restrict__ fidx, int* __restrict__ blockCnt) {
  __shared__ int h[N_APP * N_FUN];
  int tid = threadIdx.x;
  if (tid < N_APP * N_FUN) h[tid] = 0;
  __syncthreads();
  size_t o = blockIdx.x * 256 + tid;
  const int4* p = (const int4*)(fidx + o * 8);
  int4 a = p[0], b = p[1];
  atomicAdd(&h[0 * N_FUN + a.x], 1);
  atomicAdd(&h[1 * N_FUN + a.y], 1);
  atomicAdd(&h[2 * N_FUN + a.z], 1);
  atomicAdd(&h[3 * N_FUN + a.w], 1);
  atomicAdd(&h[4 * N_FUN + b.x], 1);
  atomicAdd(&h[5 * N_FUN + b.y], 1);
  atomicAdd(&h[6 * N_FUN + b.z], 1);
  atomicAdd(&h[7 * N_FUN + b.w], 1);
  __syncthreads();
  if (tid < N_APP * N_FUN) blockCnt[tid * N_BLK + blockIdx.x] = h[tid];
}

// tot[bin] = sum over blocks
__global__ void k_tot(const int* __restrict__ blockCnt, int* __restrict__ tot) {
  __shared__ int s[256];
  int tid = threadIdx.x;
  s[tid] = blockCnt[blockIdx.x * N_BLK + tid];
  __syncthreads();
  for (int o = 128; o > 0; o >>= 1) {
    if (tid < o) s[tid] += s[tid + o];
    __syncthreads();
  }
  if (tid == 0) tot[blockIdx.x] = s[0];
}

// padded group bases pb[t*17+f] + tile->f map
__global__ void k_base(const int* __restrict__ tot, int* __restrict__ pb,
                       int* __restrict__ tilef) {
  __shared__ int pbl[N_APP * 17];
  int tid = threadIdx.x;
  if (tid < N_APP) {
    int base = 0;
    for (int f = 0; f < N_FUN; ++f) {
      pbl[tid * 17 + f] = base;
      int c = tot[tid * N_FUN + f];
      base += (c + MT - 1) & ~(MT - 1);
    }
    pbl[tid * 17 + 16] = base;
  }
  __syncthreads();
  if (tid < N_APP * 17) pb[tid] = pbl[tid];
  for (int idx = tid; idx < N_APP * MAXT; idx += 256) {
    int t = idx / MAXT, q = idx - t * MAXT;
    int posn = q * MT;
    int fg = 0;
    #pragma unroll
    for (int f = 1; f < N_FUN; ++f)
      if (posn >= pbl[t * 17 + f]) fg = f;
    tilef[idx] = fg;
  }
}

// blockOff[bin*N_BLK + b] = pb-base + exclusive prefix of block counts
__global__ void k_off(const int* __restrict__ blockCnt, const int* __restrict__ pb,
                      int* __restrict__ blockOff) {
  __shared__ int s[256];
  int bin = blockIdx.x, tid = threadIdx.x;
  int c = blockCnt[bin * N_BLK + tid];
  s[tid] = c;
  __syncthreads();
  for (int o = 1; o < 256; o <<= 1) {
    int v = (tid >= o) ? s[tid - o] : 0;
    __syncthreads();
    s[tid] += v;
    __syncthreads();
  }
  int t = bin >> 4, f = bin & 15;
  blockOff[bin * N_BLK + tid] = pb[t * 17 + f] + s[tid] - c;
}

// scatter row ids via per-block LDS cursors
__global__ void k_scatter(const int* __restrict__ fidx, const int* __restrict__ blockOff,
                          int* __restrict__ perm) {
  __shared__ int cur[N_APP * N_FUN];
  int tid = threadIdx.x;
  if (tid < N_APP * N_FUN) cur[tid] = blockOff[tid * N_BLK + blockIdx.x];
  __syncthreads();
  size_t o = blockIdx.x * 256 + tid;
  const int4* p = (const int4*)(fidx + o * 8);
  int4 a = p[0], b = p[1];
  int fs[8] = {a.x, a.y, a.z, a.w, b.x, b.y, b.z, b.w};
  #pragma unroll
  for (int t = 0; t < N_APP; ++t) {
    int pos = atomicAdd(&cur[t * N_FUN + fs[t]], 1);
    perm[t * STRIDE + pos] = (int)o;
  }
}

// pos_t[o] = slot of row o in layout t (t=1..7)
__global__ void k_pos(const int* __restrict__ perm, int* __restrict__ pos) {
  int tid = blockIdx.x * 256 + threadIdx.x;
  if (tid >= 7 * STRIDE) return;
  int t = tid / STRIDE + 1, s = tid - (t - 1) * STRIDE;
  int o = perm[t * STRIDE + s];
  if (o >= 0) pos[(t - 1) * N_OBS + o] = s;
}

// outpos[t][s] = pos_{t+1}[perm[t][s]] (t=0..6); in-place for t>=1
__global__ void k_outpos(int* __restrict__ perm, const int* __restrict__ pos,
                         int* __restrict__ outpos0) {
  int tid = blockIdx.x * 256 + threadIdx.x;
  if (tid >= 7 * STRIDE) return;
  int t = tid / STRIDE, s = tid - t * STRIDE;
  int o = perm[t * STRIDE + s];
  int val = (o >= 0) ? pos[t * N_OBS + o] : -1;
  if (t == 0) outpos0[s] = val;
  else perm[t * STRIDE + s] = val;
}

// ---- LDS-staged step, async DMA in, rotation-layout carry ----
// Carry tiles are stored ROTATED in global (tile byte i == LDS byte i):
// row r's logical 16B chunk c lives at physical chunk (c + r) & 31 within
// the row. global_load_lds stages linearly; ds_read adds the rotation
// (conflict-free: banks spread across rows). Row writes stay (wrap-)
// contiguous -> store coalescing intact, no RMW amplification (r9 lesson:
// XOR permutation broke coalescing; rotation preserves it).
template <int SRC_F32, int DST_F32>
__global__ __launch_bounds__(256, 5)
void k_step(const void* __restrict__ src_, void* __restrict__ dst_,
            const unsigned short* __restrict__ Wt, const float* __restrict__ bias,
            const int* __restrict__ pb_t, const int* __restrict__ tilef_t,
            const int* __restrict__ outpos_t, const int* __restrict__ perm0) {
  __shared__ unsigned short As[MT * N_DIM];   // exactly 32768 B -> 5 blocks/CU
  int tid = threadIdx.x;
  int tile = xcd_swz(blockIdx.x, gridDim.x);
  if (tile * MT >= pb_t[16]) return;
  int f = tilef_t[tile];
  int lane = tid & 63, wave = tid >> 6, l15 = lane & 15, lq = lane >> 4;

  if (SRC_F32) {
    // gather f32 rows of x, convert, rotated ds_write (can't DMA this path)
    const int* permBase = perm0 + tile * MT;
    #pragma unroll
    for (int i = 0; i < 8; ++i) {
      int g0 = tid + i * 256;
      int row = g0 >> 5, c = g0 & 31;
      int grow = permBase[row];
      if (grow < 0) grow = 0;   // clamp; output masked at store
      const v4f* s = (const v4f*)((const float*)src_ + ((size_t)grow << 8) + (c << 3));
      v4f v0 = s[0], v1 = s[1];
      v8s val;
      val[0] = (short)f2bf(v0[0]); val[1] = (short)f2bf(v0[1]);
      val[2] = (short)f2bf(v0[2]); val[3] = (short)f2bf(v0[3]);
      val[4] = (short)f2bf(v1[0]); val[5] = (short)f2bf(v1[1]);
      val[6] = (short)f2bf(v1[2]); val[7] = (short)f2bf(v1[3]);
      *(v8s*)((char*)As + (row << 9) + (((c + row) & 31) << 4)) = val;
    }
  } else {
    // async DMA: 32 KB tile, linear (carry is pre-rotated in global)
    const char* srcT = (const char*)src_ + ((size_t)tile << 15);
    #pragma unroll
    for (int i = 0; i < 8; ++i) {
      int off = (((wave << 3) + i) << 10);   // 1 KB chunk per instruction
      __builtin_amdgcn_global_load_lds(
          (const unsigned int*)(srcT + off + (lane << 4)),
          (unsigned int*)((char*)As + off), 16, 0, 0);
    }
  }
  __syncthreads();

  v4f acc[4][4] = {};
  const unsigned short* Wf = Wt + ((size_t)f << 16);

  #pragma unroll
  for (int kk = 0; kk < 8; ++kk) {
    v8s a[4];
    #pragma unroll
    for (int mt = 0; mt < 4; ++mt) {
      int row = mt * 16 + l15;
      a[mt] = *(const v8s*)((const char*)As + (row << 9) +
                            ((((kk << 2) + lq + row) & 31) << 4));
    }
    #pragma unroll
    for (int nt = 0; nt < 4; ++nt) {
      int n = (wave << 6) + nt * 16 + l15;
      v8s bfr = *(const v8s*)(Wf + n * N_DIM + (kk << 5) + (lq << 3));
      #pragma unroll
      for (int mt = 0; mt < 4; ++mt)
        // swapped operands: D lane(l15)=row m, reg(lq*4+r)=col offset
        acc[mt][nt] = __builtin_amdgcn_mfma_f32_16x16x32_bf16(bfr, a[mt], acc[mt][nt], 0, 0, 0);
    }
  }

  const float* bf_ = bias + (f << 8) + (wave << 6) + (lq << 2);
  if (DST_F32) {
    // f32 stores: 4 lanes x 16B per 64B sector -> sector-complete, no restage
    #pragma unroll
    for (int mt = 0; mt < 4; ++mt) {
      int op = outpos_t[tile * MT + mt * 16 + l15];
      if (op < 0) continue;
      float* dr = (float*)dst_ + ((size_t)op << 8) + (wave << 6) + (lq << 2);
      #pragma unroll
      for (int nt = 0; nt < 4; ++nt) {
        v4f bv = *(const v4f*)(bf_ + (nt << 4));
        v4f o = acc[mt][nt] + bv;
        *(v4f*)(dr + (nt << 4)) = o;
      }
    }
  } else {
    __syncthreads();   // all reads of As done; reuse to stage C (bf16)
    #pragma unroll
    for (int mt = 0; mt < 4; ++mt) {
      int m = mt * 16 + l15;
      #pragma unroll
      for (int nt = 0; nt < 4; ++nt) {
        int n0 = (wave << 6) + (nt << 4) + (lq << 2);
        int c = n0 >> 3;
        v4f bv = *(const v4f*)(bf_ + (nt << 4));
        v4s pk;
        pk[0] = (short)f2bf(acc[mt][nt][0] + bv[0]);
        pk[1] = (short)f2bf(acc[mt][nt][1] + bv[1]);
        pk[2] = (short)f2bf(acc[mt][nt][2] + bv[2]);
        pk[3] = (short)f2bf(acc[mt][nt][3] + bv[3]);
        *(v4s*)((char*)As + (m << 9) + (((c + m) & 31) << 4) + ((n0 & 7) << 1)) = pk;
      }
    }
    __syncthreads();
    // full-row copy: LDS row m (rot by m) -> global slot op (rot by op);
    // per row the 32 lanes' dests ascend with one wrap -> coalesced.
    #pragma unroll
    for (int i = 0; i < 8; ++i) {
      int g0 = tid + i * 256;
      int m = g0 >> 5, c = g0 & 31;
      int op = outpos_t[tile * MT + m];
      if (op >= 0) {
        v8s v = *(const v8s*)((char*)As + (m << 9) + (((c + m) & 31) << 4));
        *(v8s*)((char*)dst_ + ((size_t)op << 9) + (((c + op) & 31) << 4)) = v;
      }
    }
  }
}

extern "C" void kernel_launch(void* const* d_in, const int* in_sizes, int n_in,
                              void* d_out, int out_size, void* d_ws, size_t ws_size,
                              hipStream_t stream) {
  const float* x = (const float*)d_in[0];
  const int* fidx = (const int*)d_in[1];
  const float* W = (const float*)d_in[2];
  const float* bias = (const float*)d_in[3];
  char* ws = (char*)d_ws;

  // carryA: STRIDE rows x 512B = 34,078,720 B (32KB tiles, rotation layout)
  unsigned short* carryA = (unsigned short*)ws;
  // overlap carryA (all dead before step 0 writes it):
  int* blockCnt = (int*)ws;                        // 131072
  int* blockOff = (int*)(ws + 131072);             // 131072
  int* tot      = (int*)(ws + 262144);             // 512
  int* pos      = (int*)(ws + 262656);             // 1,835,008
  unsigned short* Wt = (unsigned short*)(ws + 34078720);   // 2 MB
  int* perm    = (int*)(ws + 36175872);            // 2,129,920
  int* pb      = (int*)(ws + 38305792);            // 544
  int* tilef   = (int*)(ws + 38306336);            // 33,280
  int* outpos0 = (int*)(ws + 38339616);            // 266,240 (end ~38.6 MB)
  unsigned short* carryB = (unsigned short*)d_out; // bf16 scratch (34 MB of 64)

  k_init<<<(N_APP * STRIDE + 255) / 256, 256, 0, stream>>>(perm, N_APP * STRIDE);
  k_prep_w<<<(N_FUN * 65536) / 256, 256, 0, stream>>>(W, Wt);
  k_hist<<<N_BLK, 256, 0, stream>>>(fidx, blockCnt);
  k_tot<<<128, 256, 0, stream>>>(blockCnt, tot);
  k_base<<<1, 256, 0, stream>>>(tot, pb, tilef);
  k_off<<<128, 256, 0, stream>>>(blockCnt, pb, blockOff);
  k_scatter<<<N_BLK, 256, 0, stream>>>(fidx, blockOff, perm);
  k_pos<<<(7 * STRIDE + 255) / 256, 256, 0, stream>>>(perm, pos);
  k_outpos<<<(7 * STRIDE + 255) / 256, 256, 0, stream>>>(perm, pos, outpos0);

  // step 0: gather x(f32) -> carryA (layout-1 slots, rotation layout)
  k_step<1, 0><<<MAXT, 256, 0, stream>>>(x, carryA, Wt, bias, pb, tilef, outpos0, perm);
  // steps 1..6: DMA-staged bf16 -> next-layout slots (outpos in perm[t])
  for (int t = 1; t < 7; ++t) {
    const unsigned short* s = (t & 1) ? carryA : carryB;
    unsigned short* d = (t & 1) ? carryB : carryA;
    k_step<0, 0><<<MAXT, 256, 0, stream>>>(
        s, d, Wt, bias, pb + t * 17, tilef + t * MAXT, perm + t * STRIDE, nullptr);
  }
  // step 7: DMA-staged bf16 -> d_out f32 at original rows (perm[7] = row ids)
  k_step<0, 1><<<MAXT, 256, 0, stream>>>(
      carryA, d_out, Wt, bias, pb + 7 * 17, tilef + 7 * MAXT, perm + 7 * STRIDE, nullptr);
}

// Round 11
// 523.605 us; speedup vs baseline: 1.3606x; 1.3606x over previous
//
#include <hip/hip_runtime.h>
#include <hip/hip_bf16.h>
#include <stdint.h>

#define N_OBS 65536
#define N_DIM 256
#define N_FUN 16
#define N_APP 8
#define MT 64
#define STRIDE 66560          // N_OBS + N_FUN*MT
#define MAXT 1040             // STRIDE/64
#define N_BLK 256

typedef __attribute__((ext_vector_type(8))) short v8s;
typedef __attribute__((ext_vector_type(4))) short v4s;
typedef __attribute__((ext_vector_type(4))) float v4f;

__device__ __forceinline__ unsigned short f2bf(float f) {
  union { float f; uint32_t u; } v;
  v.f = f;
  uint32_t u = v.u;
  return (unsigned short)((u + 0x7FFFu + ((u >> 16) & 1u)) >> 16);
}

// bijective XCD swizzle (grid % 8 == 0): consecutive work -> same XCD L2
__device__ __forceinline__ int xcd_swz(int bid, int n) {
  int q = n >> 3;
  return (bid & 7) * q + (bid >> 3);
}

__global__ void k_init(int* __restrict__ perm, int total) {
  int tid = blockIdx.x * 256 + threadIdx.x;
  if (tid < total) perm[tid] = -1;
}

// W (f,d,e) f32 -> WtF in MFMA B-FRAGMENT order:
// WtF[((f*4+wave)*4+nt)*8+kk][lane][j] = W[f][kk*32+(lane>>4)*8+j][wave*64+nt*16+(lane&15)]
// so each fragment load in k_step is one coalesced 1KB instruction.
__global__ void k_prep_w(const float* __restrict__ W, unsigned short* __restrict__ WtF) {
  int t = blockIdx.x * 256 + threadIdx.x;   // 131072 threads
  int lane = t & 63;
  int kk = (t >> 6) & 7;
  int nt = (t >> 9) & 3;
  int wave = (t >> 11) & 3;
  int f = (t >> 13) & 15;
  int n = (wave << 6) + (nt << 4) + (lane & 15);
  int kb = (kk << 5) + ((lane >> 4) << 3);
  unsigned short* o = WtF + ((size_t)t << 3);
  #pragma unroll
  for (int j = 0; j < 8; ++j)
    o[j] = f2bf(W[(f << 16) + ((kb + j) << 8) + n]);
}

// per-block histogram: blockCnt[bin*N_BLK + block], bin = t*16+f (128 bins)
__global__ void k_hist(const int* __restrict__ fidx, int* __restrict__ blockCnt) {
  __shared__ int h[N_APP * N_FUN];
  int tid = threadIdx.x;
  if (tid < N_APP * N_FUN) h[tid] = 0;
  __syncthreads();
  size_t o = blockIdx.x * 256 + tid;
  const int4* p = (const int4*)(fidx + o * 8);
  int4 a = p[0], b = p[1];
  atomicAdd(&h[0 * N_FUN + a.x], 1);
  atomicAdd(&h[1 * N_FUN + a.y], 1);
  atomicAdd(&h[2 * N_FUN + a.z], 1);
  atomicAdd(&h[3 * N_FUN + a.w], 1);
  atomicAdd(&h[4 * N_FUN + b.x], 1);
  atomicAdd(&h[5 * N_FUN + b.y], 1);
  atomicAdd(&h[6 * N_FUN + b.z], 1);
  atomicAdd(&h[7 * N_FUN + b.w], 1);
  __syncthreads();
  if (tid < N_APP * N_FUN) blockCnt[tid * N_BLK + blockIdx.x] = h[tid];
}

// tot[bin] = sum over blocks
__global__ void k_tot(const int* __restrict__ blockCnt, int* __restrict__ tot) {
  __shared__ int s[256];
  int tid = threadIdx.x;
  s[tid] = blockCnt[blockIdx.x * N_BLK + tid];
  __syncthreads();
  for (int o = 128; o > 0; o >>= 1) {
    if (tid < o) s[tid] += s[tid + o];
    __syncthreads();
  }
  if (tid == 0) tot[blockIdx.x] = s[0];
}

// padded group bases pb[t*17+f] + tile->f map
__global__ void k_base(const int* __restrict__ tot, int* __restrict__ pb,
                       int* __restrict__ tilef) {
  __shared__ int pbl[N_APP * 17];
  int tid = threadIdx.x;
  if (tid < N_APP) {
    int base = 0;
    for (int f = 0; f < N_FUN; ++f) {
      pbl[tid * 17 + f] = base;
      int c = tot[tid * N_FUN + f];
      base += (c + MT - 1) & ~(MT - 1);
    }
    pbl[tid * 17 + 16] = base;
  }
  __syncthreads();
  if (tid < N_APP * 17) pb[tid] = pbl[tid];
  for (int idx = tid; idx < N_APP * MAXT; idx += 256) {
    int t = idx / MAXT, q = idx - t * MAXT;
    int posn = q * MT;
    int fg = 0;
    #pragma unroll
    for (int f = 1; f < N_FUN; ++f)
      if (posn >= pbl[t * 17 + f]) fg = f;
    tilef[idx] = fg;
  }
}

// blockOff[bin*N_BLK + b] = pb-base + exclusive prefix of block counts
__global__ void k_off(const int* __restrict__ blockCnt, const int* __restrict__ pb,
                      int* __restrict__ blockOff) {
  __shared__ int s[256];
  int bin = blockIdx.x, tid = threadIdx.x;
  int c = blockCnt[bin * N_BLK + tid];
  s[tid] = c;
  __syncthreads();
  for (int o = 1; o < 256; o <<= 1) {
    int v = (tid >= o) ? s[tid - o] : 0;
    __syncthreads();
    s[tid] += v;
    __syncthreads();
  }
  int t = bin >> 4, f = bin & 15;
  blockOff[bin * N_BLK + tid] = pb[t * 17 + f] + s[tid] - c;
}

// scatter row ids via per-block LDS cursors
__global__ void k_scatter(const int* __restrict__ fidx, const int* __restrict__ blockOff,
                          int* __restrict__ perm) {
  __shared__ int cur[N_APP * N_FUN];
  int tid = threadIdx.x;
  if (tid < N_APP * N_FUN) cur[tid] = blockOff[tid * N_BLK + blockIdx.x];
  __syncthreads();
  size_t o = blockIdx.x * 256 + tid;
  const int4* p = (const int4*)(fidx + o * 8);
  int4 a = p[0], b = p[1];
  int fs[8] = {a.x, a.y, a.z, a.w, b.x, b.y, b.z, b.w};
  #pragma unroll
  for (int t = 0; t < N_APP; ++t) {
    int pos = atomicAdd(&cur[t * N_FUN + fs[t]], 1);
    perm[t * STRIDE + pos] = (int)o;
  }
}

// pos_t[o] = slot of row o in layout t (t=1..7)
__global__ void k_pos(const int* __restrict__ perm, int* __restrict__ pos) {
  int tid = blockIdx.x * 256 + threadIdx.x;
  if (tid >= 7 * STRIDE) return;
  int t = tid / STRIDE + 1, s = tid - (t - 1) * STRIDE;
  int o = perm[t * STRIDE + s];
  if (o >= 0) pos[(t - 1) * N_OBS + o] = s;
}

// outpos[t][s] = pos_{t+1}[perm[t][s]] (t=0..6); in-place for t>=1
__global__ void k_outpos(int* __restrict__ perm, const int* __restrict__ pos,
                         int* __restrict__ outpos0) {
  int tid = blockIdx.x * 256 + threadIdx.x;
  if (tid >= 7 * STRIDE) return;
  int t = tid / STRIDE, s = tid - t * STRIDE;
  int o = perm[t * STRIDE + s];
  int val = (o >= 0) ? pos[t * N_OBS + o] : -1;
  if (t == 0) outpos0[s] = val;
  else perm[t * STRIDE + s] = val;
}

// ---- LDS-staged step: DMA in (pre-swizzled SOURCE), coalesced B-frags,
//      LINEAR global carry (r3-proven write path) ----
// Global carry layout is plain row-major [slot][256]. Staging DMA keeps the
// LDS destination linear (HW requirement) but each lane fetches from the
// XOR-inverse global offset, so LDS holds the XOR-swizzled tile (m173
// pattern); ds_reads use the r3 swizzle. Stores to global are strictly
// linear-in-lane (r8/r9/r10 lesson: any in-row store permutation -> 3.5-5x
// write amplification).
template <int SRC_F32, int DST_F32>
__global__ __launch_bounds__(256, 5)
void k_step(const void* __restrict__ src_, void* __restrict__ dst_,
            const unsigned short* __restrict__ WtF, const float* __restrict__ bias,
            const int* __restrict__ pb_t, const int* __restrict__ tilef_t,
            const int* __restrict__ outpos_t, const int* __restrict__ perm0) {
  __shared__ unsigned short As[MT * N_DIM];   // exactly 32768 B -> 5 blocks/CU
  int tid = threadIdx.x;
  int tile = xcd_swz(blockIdx.x, gridDim.x);
  if (tile * MT >= pb_t[16]) return;
  int f = tilef_t[tile];
  int lane = tid & 63, wave = tid >> 6, l15 = lane & 15, lq = lane >> 4;

  if (SRC_F32) {
    // gather f32 rows of x, convert, swizzled ds_write (can't DMA-convert)
    const int* permBase = perm0 + tile * MT;
    #pragma unroll
    for (int i = 0; i < 8; ++i) {
      int g0 = tid + i * 256;
      int row = g0 >> 5, c = g0 & 31;
      int grow = permBase[row];
      if (grow < 0) grow = 0;   // clamp; output masked at store
      const v4f* s = (const v4f*)((const float*)src_ + ((size_t)grow << 8) + (c << 3));
      v4f v0 = s[0], v1 = s[1];
      v8s val;
      val[0] = (short)f2bf(v0[0]); val[1] = (short)f2bf(v0[1]);
      val[2] = (short)f2bf(v0[2]); val[3] = (short)f2bf(v0[3]);
      val[4] = (short)f2bf(v1[0]); val[5] = (short)f2bf(v1[1]);
      val[6] = (short)f2bf(v1[2]); val[7] = (short)f2bf(v1[3]);
      *(v8s*)((char*)As + (row << 9) + ((c ^ (row & 7)) << 4)) = val;
    }
  } else {
    // async DMA, LDS dest linear; per-lane SOURCE pre-swizzled so that LDS
    // physical chunk pc of row r receives logical chunk (pc ^ (r&7)).
    const char* srcT = (const char*)src_ + ((size_t)tile << 15);
    #pragma unroll
    for (int i = 0; i < 8; ++i) {
      int off = (((wave << 3) + i) << 10);         // wave-uniform LDS base
      int db = off + (lane << 4);                  // this lane's LDS byte
      int row = db >> 9;
      int pc = (db >> 4) & 31;
      __builtin_amdgcn_global_load_lds(
          (const unsigned int*)(srcT + (row << 9) + ((pc ^ (row & 7)) << 4)),
          (unsigned int*)((char*)As + off), 16, 0, 0);
    }
  }
  __syncthreads();

  v4f acc[4][4] = {};
  // fragment-ordered B: fragment (nt,kk) = 1KB at consecutive lane*16
  const unsigned short* Wfr = WtF + ((size_t)f << 16) + (wave << 14) + (lane << 3);

  #pragma unroll
  for (int kk = 0; kk < 8; ++kk) {
    v8s a[4];
    #pragma unroll
    for (int mt = 0; mt < 4; ++mt) {
      int row = mt * 16 + l15;
      a[mt] = *(const v8s*)((const char*)As + (row << 9) +
                            ((((kk << 2) + lq) ^ (row & 7)) << 4));
    }
    #pragma unroll
    for (int nt = 0; nt < 4; ++nt) {
      v8s bfr = *(const v8s*)(Wfr + (((nt << 3) + kk) << 9));
      #pragma unroll
      for (int mt = 0; mt < 4; ++mt)
        // swapped operands: D lane(l15)=row m, reg(lq*4+r)=col offset
        acc[mt][nt] = __builtin_amdgcn_mfma_f32_16x16x32_bf16(bfr, a[mt], acc[mt][nt], 0, 0, 0);
    }
  }

  const float* bf_ = bias + (f << 8) + (wave << 6) + (lq << 2);
  if (DST_F32) {
    // f32 stores: 4 lanes x 16B per 64B sector -> sector-complete
    #pragma unroll
    for (int mt = 0; mt < 4; ++mt) {
      int op = outpos_t[tile * MT + mt * 16 + l15];
      if (op < 0) continue;
      float* dr = (float*)dst_ + ((size_t)op << 8) + (wave << 6) + (lq << 2);
      #pragma unroll
      for (int nt = 0; nt < 4; ++nt) {
        v4f bv = *(const v4f*)(bf_ + (nt << 4));
        v4f o = acc[mt][nt] + bv;
        *(v4f*)(dr + (nt << 4)) = o;
      }
    }
  } else {
    __syncthreads();   // all reads of As done; reuse to stage C (bf16)
    #pragma unroll
    for (int mt = 0; mt < 4; ++mt) {
      int m = mt * 16 + l15;
      #pragma unroll
      for (int nt = 0; nt < 4; ++nt) {
        int n0 = (wave << 6) + (nt << 4) + (lq << 2);
        int c = n0 >> 3;
        v4f bv = *(const v4f*)(bf_ + (nt << 4));
        v4s pk;
        pk[0] = (short)f2bf(acc[mt][nt][0] + bv[0]);
        pk[1] = (short)f2bf(acc[mt][nt][1] + bv[1]);
        pk[2] = (short)f2bf(acc[mt][nt][2] + bv[2]);
        pk[3] = (short)f2bf(acc[mt][nt][3] + bv[3]);
        *(v4s*)((char*)As + (m << 9) + ((c ^ (m & 7)) << 4) + ((n0 & 7) << 1)) = pk;
      }
    }
    __syncthreads();
    // full-row copy: LDS row m (XOR by m) -> global slot op, LINEAR in c
    #pragma unroll
    for (int i = 0; i < 8; ++i) {
      int g0 = tid + i * 256;
      int m = g0 >> 5, c = g0 & 31;
      int op = outpos_t[tile * MT + m];
      if (op >= 0) {
        v8s v = *(const v8s*)((char*)As + (m << 9) + ((c ^ (m & 7)) << 4));
        *(v8s*)((unsigned short*)dst_ + ((size_t)op << 8) + (c << 3)) = v;
      }
    }
  }
}

extern "C" void kernel_launch(void* const* d_in, const int* in_sizes, int n_in,
                              void* d_out, int out_size, void* d_ws, size_t ws_size,
                              hipStream_t stream) {
  const float* x = (const float*)d_in[0];
  const int* fidx = (const int*)d_in[1];
  const float* W = (const float*)d_in[2];
  const float* bias = (const float*)d_in[3];
  char* ws = (char*)d_ws;

  // carryA: STRIDE rows x 512B = 34,078,720 B (plain row-major)
  unsigned short* carryA = (unsigned short*)ws;
  // overlap carryA (all dead before step 0 writes it):
  int* blockCnt = (int*)ws;                        // 131072
  int* blockOff = (int*)(ws + 131072);             // 131072
  int* tot      = (int*)(ws + 262144);             // 512
  int* pos      = (int*)(ws + 262656);             // 1,835,008
  unsigned short* WtF = (unsigned short*)(ws + 34078720);  // 2 MB, fragment order
  int* perm    = (int*)(ws + 36175872);            // 2,129,920
  int* pb      = (int*)(ws + 38305792);            // 544
  int* tilef   = (int*)(ws + 38306336);            // 33,280
  int* outpos0 = (int*)(ws + 38339616);            // 266,240 (end ~38.6 MB)
  unsigned short* carryB = (unsigned short*)d_out; // bf16 scratch (34 MB of 64)

  k_init<<<(N_APP * STRIDE + 255) / 256, 256, 0, stream>>>(perm, N_APP * STRIDE);
  k_prep_w<<<512, 256, 0, stream>>>(W, WtF);
  k_hist<<<N_BLK, 256, 0, stream>>>(fidx, blockCnt);
  k_tot<<<128, 256, 0, stream>>>(blockCnt, tot);
  k_base<<<1, 256, 0, stream>>>(tot, pb, tilef);
  k_off<<<128, 256, 0, stream>>>(blockCnt, pb, blockOff);
  k_scatter<<<N_BLK, 256, 0, stream>>>(fidx, blockOff, perm);
  k_pos<<<(7 * STRIDE + 255) / 256, 256, 0, stream>>>(perm, pos);
  k_outpos<<<(7 * STRIDE + 255) / 256, 256, 0, stream>>>(perm, pos, outpos0);

  // step 0: gather x(f32) -> carryA (layout-1 slots, linear rows)
  k_step<1, 0><<<MAXT, 256, 0, stream>>>(x, carryA, WtF, bias, pb, tilef, outpos0, perm);
  // steps 1..6: DMA-staged bf16 -> next-layout slots (outpos in perm[t])
  for (int t = 1; t < 7; ++t) {
    const unsigned short* s = (t & 1) ? carryA : carryB;
    unsigned short* d = (t & 1) ? carryB : carryA;
    k_step<0, 0><<<MAXT, 256, 0, stream>>>(
        s, d, WtF, bias, pb + t * 17, tilef + t * MAXT, perm + t * STRIDE, nullptr);
  }
  // step 7: DMA-staged bf16 -> d_out f32 at original rows (perm[7] = row ids)
  k_step<0, 1><<<MAXT, 256, 0, stream>>>(
      carryA, d_out, WtF, bias, pb + 7 * 17, tilef + 7 * MAXT, perm + 7 * STRIDE, nullptr);
}